// Round 3
// baseline (230.213 us; speedup 1.0000x reference)
//
#include <hip/hip_runtime.h>
#include <stdint.h>

#define S_LEN 4096
#define D_EMB 1024
#define NH 16
#define DHEAD 64
#define N3 3072

typedef __attribute__((ext_vector_type(8))) short short8;
typedef __attribute__((ext_vector_type(4))) float f32x4;

// workspace layout (ushort elements)
#define OFF_XB    0u         // x bf16 [4096][1024]; reused as chunk-1 attn partial after gemm1
#define OFF_WINT  4194304u   // W_in^T bf16; first 1MB reused as attn m/l after gemm1
#define OFF_WOUTT 7340032u   // W_out^T bf16 (live until gemm2)
#define OFF_Q     8388608u   // q [H][S][64], k [H][S][64], v^T [H][64][S], each 4194304
#define OFF_ATTN  20971520u  // chunk-0 attn partial / combined attn out [4096][1024]

// 0.125 (1/sqrt(64)) * log2(e): QK^T then directly feeds exp2
#define QSCALE 0.1803368801111204f
#define DEFER_THR 11.0f

__device__ __forceinline__ unsigned short f2bf(float f) {
  unsigned u = __float_as_uint(f);
  unsigned r = u + 0x7FFFu + ((u >> 16) & 1u);
  return (unsigned short)(r >> 16);
}
__device__ __forceinline__ float bf2f(unsigned short b) {
  return __uint_as_float(((unsigned)b) << 16);
}

// ---------------- elementwise f32 -> bf16 ----------------
__global__ __launch_bounds__(256) void cvt_bf16_kernel(const float* __restrict__ src,
                                                       ushort* __restrict__ dst, int n) {
  int i = (blockIdx.x * 256 + threadIdx.x) * 4;
  if (i + 3 < n) {
    float4 v = *(const float4*)(src + i);
    ushort4 o;
    o.x = f2bf(v.x); o.y = f2bf(v.y); o.z = f2bf(v.z); o.w = f2bf(v.w);
    *(ushort4*)(dst + i) = o;
  }
}

// ---------------- transpose + cast: src[R][C] f32 -> dst[C][R] bf16 ----------------
__global__ __launch_bounds__(256) void transpose_cvt_kernel(const float* __restrict__ src,
                                                            ushort* __restrict__ dst,
                                                            int R, int C) {
  __shared__ float tile[32][33];
  int tx = threadIdx.x & 31, ty = threadIdx.x >> 5;
  int c0 = blockIdx.x * 32, r0 = blockIdx.y * 32;
#pragma unroll
  for (int i = 0; i < 32; i += 8)
    tile[ty + i][tx] = src[(size_t)(r0 + ty + i) * C + c0 + tx];
  __syncthreads();
#pragma unroll
  for (int i = 0; i < 32; i += 8)
    dst[(size_t)(c0 + ty + i) * R + r0 + tx] = f2bf(tile[tx][ty + i]);
}

// ---------------- GEMM: C[M][N] = A[M][K] * Bt[N][K]^T + bias ----------------
// MODE 0: scatter into q (pre-scaled by QSCALE)/k head-major bf16 + v TRANSPOSED ([H][64][S]).
// MODE 1: plain f32 out.
#define BK 64
#define LDT 72  // padded stride (144B, multiple of 16B)

template <int MODE>
__global__ __launch_bounds__(256) void gemm_bt_kernel(const ushort* __restrict__ A,
                                                      const ushort* __restrict__ Bt,
                                                      const float* __restrict__ bias,
                                                      ushort* __restrict__ o16,
                                                      float* __restrict__ o32,
                                                      int N, int K) {
  __shared__ ushort As[128 * LDT];
  __shared__ ushort Bs[128 * LDT];
  int tid = threadIdx.x, w = tid >> 6, lane = tid & 63;
  int wr = w >> 1, wc = w & 1;
  int l15 = lane & 15, g = lane >> 4;
  int bm = blockIdx.y * 128, bn = blockIdx.x * 128;
  f32x4 acc[4][4];
#pragma unroll
  for (int m = 0; m < 4; ++m)
#pragma unroll
    for (int n = 0; n < 4; ++n) acc[m][n] = (f32x4){0.f, 0.f, 0.f, 0.f};

  int sr = tid >> 1;
  int sc = (tid & 1) * 32;

  for (int k0 = 0; k0 < K; k0 += BK) {
    __syncthreads();
    {
      const ushort* ga = A + (size_t)(bm + sr) * K + k0 + sc;
      const ushort* gb = Bt + (size_t)(bn + sr) * K + k0 + sc;
      short8 ra[4], rb[4];
#pragma unroll
      for (int i = 0; i < 4; ++i) {
        ra[i] = *(const short8*)(ga + i * 8);
        rb[i] = *(const short8*)(gb + i * 8);
      }
#pragma unroll
      for (int i = 0; i < 4; ++i) {
        *(short8*)&As[sr * LDT + sc + i * 8] = ra[i];
        *(short8*)&Bs[sr * LDT + sc + i * 8] = rb[i];
      }
    }
    __syncthreads();
    short8 a[4][2], b[4][2];
#pragma unroll
    for (int m = 0; m < 4; ++m)
#pragma unroll
      for (int t = 0; t < 2; ++t)
        a[m][t] = *(const short8*)&As[(wr * 64 + m * 16 + l15) * LDT + t * 32 + g * 8];
#pragma unroll
    for (int n = 0; n < 4; ++n)
#pragma unroll
      for (int t = 0; t < 2; ++t)
        b[n][t] = *(const short8*)&Bs[(wc * 64 + n * 16 + l15) * LDT + t * 32 + g * 8];
#pragma unroll
    for (int m = 0; m < 4; ++m)
#pragma unroll
      for (int n = 0; n < 4; ++n)
#pragma unroll
        for (int t = 0; t < 2; ++t)
          acc[m][n] = __builtin_amdgcn_mfma_f32_16x16x32_bf16(a[m][t], b[n][t], acc[m][n], 0, 0, 0);
  }

#pragma unroll
  for (int m = 0; m < 4; ++m) {
    int rbase = bm + wr * 64 + m * 16 + g * 4;
#pragma unroll
    for (int n = 0; n < 4; ++n) {
      int c = bn + wc * 64 + n * 16 + l15;
      float bv = bias[c];
      if (MODE == 0) {
        int which = c >> 10, cc = c & 1023, hh = cc >> 6, dcol = cc & 63;
        if (which == 2) {
          ushort4 o;
          o.x = f2bf(acc[m][n][0] + bv);
          o.y = f2bf(acc[m][n][1] + bv);
          o.z = f2bf(acc[m][n][2] + bv);
          o.w = f2bf(acc[m][n][3] + bv);
          *(ushort4*)&o16[8388608u + (size_t)hh * (DHEAD * (size_t)S_LEN) +
                          (size_t)dcol * S_LEN + rbase] = o;
        } else {
          float qs = (which == 0) ? QSCALE : 1.0f;
          ushort* dst = o16 + (size_t)which * 4194304u +
                        (size_t)hh * (S_LEN * DHEAD) + dcol;
#pragma unroll
          for (int j = 0; j < 4; ++j)
            dst[(size_t)(rbase + j) * DHEAD] = f2bf((acc[m][n][j] + bv) * qs);
        }
      } else {
#pragma unroll
        for (int j = 0; j < 4; ++j)
          o32[(size_t)(rbase + j) * N + c] = acc[m][n][j] + bv;
      }
    }
  }
}

// ---------------- causal flash attention, split-KV x2 ----------------
// Q (pre-scaled), K: [H][S][64].  Vt: [H][64][S].
// Block bid: c = bid&1 (KV chunk, tiles it%2==c), p = (bid>>1)&31, h = bid>>6.
// Handles q-tiles {p, 63-p}. Writes normalized partial O (bf16) + (m,l) per row.
__global__ __launch_bounds__(256) void attn_kernel(const ushort* __restrict__ Q,
                                                   const ushort* __restrict__ Kg,
                                                   const ushort* __restrict__ Vtg,
                                                   ushort* __restrict__ P0,
                                                   ushort* __restrict__ P1,
                                                   float2* __restrict__ ml) {
  __shared__ ushort Ks[64 * LDT];
  __shared__ ushort Vs[64 * LDT];
  __shared__ ushort Pl[4][16 * LDT];
  int bid = blockIdx.x;
  int c = bid & 1, p = (bid >> 1) & 31, h = bid >> 6;
  int tid = threadIdx.x, w = tid >> 6, lane = tid & 63;
  int l15 = lane & 15, g = lane >> 4;
  const ushort* qh = Q + (size_t)h * (S_LEN * DHEAD);
  const ushort* kh = Kg + (size_t)h * (S_LEN * DHEAD);
  const ushort* vh = Vtg + (size_t)h * (DHEAD * (size_t)S_LEN);
  int sr = tid >> 2;
  int scc = (tid & 3) * 16;
  ushort* pw = Pl[w];
  ushort* Pc = c ? P1 : P0;

#pragma unroll 1
  for (int half = 0; half < 2; ++half) {
    int qt = half ? (63 - p) : p;
    int q0 = qt * 64;

    if (c > qt) {  // empty chunk (only qt=0,c=1): zero partial
      int row = q0 + (tid >> 2);
      int cb = (tid & 3) * 16;
      short8 z = (short8){0, 0, 0, 0, 0, 0, 0, 0};
      *(short8*)&Pc[(size_t)row * D_EMB + h * DHEAD + cb] = z;
      *(short8*)&Pc[(size_t)row * D_EMB + h * DHEAD + cb + 8] = z;
      if (tid < 64)
        ml[(size_t)(c * NH + h) * S_LEN + q0 + tid] = make_float2(-1e30f, 0.f);
      continue;
    }

    short8 aq[2];
    {
      int qrow = q0 + w * 16 + l15;
#pragma unroll
      for (int t = 0; t < 2; ++t)
        aq[t] = *(const short8*)&qh[(size_t)qrow * DHEAD + t * 32 + g * 8];
    }
    f32x4 acc_o[4];
#pragma unroll
    for (int dt = 0; dt < 4; ++dt) acc_o[dt] = (f32x4){0.f, 0.f, 0.f, 0.f};
    float mstate[4], lstate[4];
#pragma unroll
    for (int j = 0; j < 4; ++j) { mstate[j] = -1e30f; lstate[j] = 0.f; }
    int qr_base = q0 + w * 16 + g * 4;

    // prologue: stage tile c
    {
      int kv0 = c * 64;
      short8 ka = *(const short8*)&kh[(size_t)(kv0 + sr) * DHEAD + scc];
      short8 kb = *(const short8*)&kh[(size_t)(kv0 + sr) * DHEAD + scc + 8];
      short8 va = *(const short8*)&vh[(size_t)sr * S_LEN + kv0 + scc];
      short8 vb = *(const short8*)&vh[(size_t)sr * S_LEN + kv0 + scc + 8];
      __syncthreads();   // previous half's readers done
      *(short8*)&Ks[sr * LDT + scc] = ka;
      *(short8*)&Ks[sr * LDT + scc + 8] = kb;
      *(short8*)&Vs[sr * LDT + scc] = va;
      *(short8*)&Vs[sr * LDT + scc + 8] = vb;
      __syncthreads();
    }

    for (int it = c; it <= qt; it += 2) {
      int kv0 = it * 64;
      bool more = (it + 2 <= qt);
      short8 nka, nkb, nva, nvb;
      if (more) {
        int kv1 = kv0 + 128;
        nka = *(const short8*)&kh[(size_t)(kv1 + sr) * DHEAD + scc];
        nkb = *(const short8*)&kh[(size_t)(kv1 + sr) * DHEAD + scc + 8];
        nva = *(const short8*)&vh[(size_t)sr * S_LEN + kv1 + scc];
        nvb = *(const short8*)&vh[(size_t)sr * S_LEN + kv1 + scc + 8];
      }

      // QK^T (output already in log2 units via pre-scaled Q)
      f32x4 accs[4];
#pragma unroll
      for (int ct = 0; ct < 4; ++ct) accs[ct] = (f32x4){0.f, 0.f, 0.f, 0.f};
#pragma unroll
      for (int ct = 0; ct < 4; ++ct)
#pragma unroll
        for (int t = 0; t < 2; ++t) {
          short8 kf = *(const short8*)&Ks[(ct * 16 + l15) * LDT + t * 32 + g * 8];
          accs[ct] = __builtin_amdgcn_mfma_f32_16x16x32_bf16(aq[t], kf, accs[ct], 0, 0, 0);
        }

      float sv[4][4];
      if (it == qt) {
#pragma unroll
        for (int ct = 0; ct < 4; ++ct) {
          int key = kv0 + ct * 16 + l15;
#pragma unroll
          for (int j = 0; j < 4; ++j)
            sv[ct][j] = (key > qr_base + j) ? -1e30f : accs[ct][j];
        }
      } else {
#pragma unroll
        for (int ct = 0; ct < 4; ++ct)
#pragma unroll
          for (int j = 0; j < 4; ++j) sv[ct][j] = accs[ct][j];
      }

      // row max (per j), then T13 defer-max rescale
      float pm[4];
#pragma unroll
      for (int j = 0; j < 4; ++j) {
        float mx = fmaxf(fmaxf(sv[0][j], sv[1][j]), fmaxf(sv[2][j], sv[3][j]));
#pragma unroll
        for (int off = 1; off < 16; off <<= 1) mx = fmaxf(mx, __shfl_xor(mx, off));
        pm[j] = mx;
      }
      int ok = (pm[0] <= mstate[0] + DEFER_THR) & (pm[1] <= mstate[1] + DEFER_THR) &
               (pm[2] <= mstate[2] + DEFER_THR) & (pm[3] <= mstate[3] + DEFER_THR);
      if (!__all(ok)) {
#pragma unroll
        for (int j = 0; j < 4; ++j) {
          float mnew = fmaxf(mstate[j], pm[j]);
          float corr = __builtin_amdgcn_exp2f(mstate[j] - mnew);
          lstate[j] *= corr;
          mstate[j] = mnew;
#pragma unroll
          for (int dt = 0; dt < 4; ++dt) acc_o[dt][j] *= corr;
        }
      }
#pragma unroll
      for (int j = 0; j < 4; ++j) {
        float rs = 0.f;
#pragma unroll
        for (int ct = 0; ct < 4; ++ct) {
          float pe = __builtin_amdgcn_exp2f(sv[ct][j] - mstate[j]);
          sv[ct][j] = pe;
          rs += pe;
        }
#pragma unroll
        for (int off = 1; off < 16; off <<= 1) rs += __shfl_xor(rs, off);
        lstate[j] += rs;
      }
#pragma unroll
      for (int ct = 0; ct < 4; ++ct)
#pragma unroll
        for (int j = 0; j < 4; ++j)
          pw[(g * 4 + j) * LDT + ct * 16 + l15] = f2bf(sv[ct][j]);
      asm volatile("s_waitcnt lgkmcnt(0)" ::: "memory");

#pragma unroll
      for (int dt = 0; dt < 4; ++dt)
#pragma unroll
        for (int t = 0; t < 2; ++t) {
          short8 pa = *(const short8*)&pw[l15 * LDT + t * 32 + g * 8];
          short8 vf = *(const short8*)&Vs[(dt * 16 + l15) * LDT + t * 32 + g * 8];
          acc_o[dt] = __builtin_amdgcn_mfma_f32_16x16x32_bf16(pa, vf, acc_o[dt], 0, 0, 0);
        }

      __syncthreads();
      if (more) {
        *(short8*)&Ks[sr * LDT + scc] = nka;
        *(short8*)&Ks[sr * LDT + scc + 8] = nkb;
        *(short8*)&Vs[sr * LDT + scc] = nva;
        *(short8*)&Vs[sr * LDT + scc + 8] = nvb;
        __syncthreads();
      }
    }

    // epilogue: normalized partial + (m,l)
    float rl[4];
#pragma unroll
    for (int j = 0; j < 4; ++j) rl[j] = (lstate[j] > 0.f) ? 1.f / lstate[j] : 0.f;
#pragma unroll
    for (int dt = 0; dt < 4; ++dt)
#pragma unroll
      for (int j = 0; j < 4; ++j) {
        int row = qr_base + j;
        Pc[(size_t)row * D_EMB + h * DHEAD + dt * 16 + l15] = f2bf(acc_o[dt][j] * rl[j]);
      }
    if (l15 == 0) {
#pragma unroll
      for (int j = 0; j < 4; ++j)
        ml[(size_t)(c * NH + h) * S_LEN + qr_base + j] = make_float2(mstate[j], lstate[j]);
    }
  }
}

// ---------------- combine the two KV-chunk partials ----------------
__global__ __launch_bounds__(256) void combine_kernel(const ushort* __restrict__ P0,
                                                      const ushort* __restrict__ P1,
                                                      const float2* __restrict__ ml,
                                                      ushort* __restrict__ Out) {
  int idx = blockIdx.x * 256 + threadIdx.x;
  int row = idx >> 7;
  int cb = (idx & 127) * 8;
  int h = cb >> 6;
  float2 e0 = ml[(size_t)h * S_LEN + row];
  float2 e1 = ml[(size_t)(NH + h) * S_LEN + row];
  float mm = fmaxf(e0.x, e1.x);
  float w0 = e0.y * __builtin_amdgcn_exp2f(e0.x - mm);
  float w1 = e1.y * __builtin_amdgcn_exp2f(e1.x - mm);
  float inv = 1.f / (w0 + w1);
  w0 *= inv; w1 *= inv;
  size_t base = (size_t)row * D_EMB + cb;
  short8 a = *(const short8*)&P0[base];
  short8 b = *(const short8*)&P1[base];
  short8 o;
#pragma unroll
  for (int i = 0; i < 8; ++i) {
    float fv = w0 * bf2f((unsigned short)a[i]) + w1 * bf2f((unsigned short)b[i]);
    o[i] = (short)f2bf(fv);
  }
  *(short8*)&Out[base] = o;
}

extern "C" void kernel_launch(void* const* d_in, const int* in_sizes, int n_in,
                              void* d_out, int out_size, void* d_ws, size_t ws_size,
                              hipStream_t stream) {
  const float* x = (const float*)d_in[0];
  const float* W_in = (const float*)d_in[1];
  const float* b_in = (const float*)d_in[2];
  const float* W_out = (const float*)d_in[3];
  const float* b_out = (const float*)d_in[4];
  float* out = (float*)d_out;
  ushort* ws = (ushort*)d_ws;

  ushort* P0 = ws + OFF_ATTN;                 // chunk-0 partial / combined result
  ushort* P1 = ws + OFF_XB;                   // chunk-1 partial (x_bf16 dead after gemm1)
  float2* ml = (float2*)(ws + OFF_WINT);      // (m,l) per (chunk,head,row); W_in^T dead after gemm1

  // 1. x -> bf16
  cvt_bf16_kernel<<<4096, 256, 0, stream>>>(x, ws + OFF_XB, S_LEN * D_EMB);
  // 2. W_in^T, W_out^T -> bf16
  transpose_cvt_kernel<<<dim3(N3 / 32, D_EMB / 32), 256, 0, stream>>>(W_in, ws + OFF_WINT, D_EMB, N3);
  transpose_cvt_kernel<<<dim3(D_EMB / 32, D_EMB / 32), 256, 0, stream>>>(W_out, ws + OFF_WOUTT, D_EMB, D_EMB);
  // 3. qkv = x @ W_in + b_in -> q (pre-scaled) / k head-major + v transposed
  gemm_bt_kernel<0><<<dim3(N3 / 128, S_LEN / 128), 256, 0, stream>>>(
      ws + OFF_XB, ws + OFF_WINT, b_in, ws + OFF_Q, nullptr, N3, D_EMB);
  // 4. causal attention, split-KV x2 (pair-balanced)
  attn_kernel<<<NH * 64, 256, 0, stream>>>(
      ws + OFF_Q, ws + OFF_Q + 4194304u, ws + OFF_Q + 8388608u, P0, P1, ml);
  // 5. combine partials -> P0
  combine_kernel<<<(S_LEN * D_EMB / 8) / 256, 256, 0, stream>>>(P0, P1, ml, P0);
  // 6. out = attn @ W_out + b_out
  gemm_bt_kernel<1><<<dim3(D_EMB / 128, S_LEN / 128), 256, 0, stream>>>(
      P0, ws + OFF_WOUTT, b_out, nullptr, out, D_EMB, D_EMB);
}

// Round 4
// 203.051 us; speedup vs baseline: 1.1338x; 1.1338x over previous
//
#include <hip/hip_runtime.h>
#include <stdint.h>

#define S_LEN 4096
#define D_EMB 1024
#define NH 16
#define DHEAD 64
#define N3 3072

typedef __attribute__((ext_vector_type(8))) short short8;
typedef __attribute__((ext_vector_type(4))) short short4v;
typedef __attribute__((ext_vector_type(4))) float f32x4;

// workspace layout (ushort elements)
#define OFF_XB    0u         // x bf16; reused as chunk-1 attn partial after gemm1
#define OFF_WINT  4194304u   // W_in^T bf16; reused as attn m/l after gemm1
#define OFF_WOUTT 7340032u   // W_out^T bf16 (live until gemm2)
#define OFF_Q     8388608u   // q [H][S][64], k [H][S][64], v^T [H][64][S]
#define OFF_ATTN  20971520u  // chunk-0 attn partial / combined attn out

// 0.125 (1/sqrt(64)) * log2(e)
#define QSCALE 0.1803368801111204f
#define DEFER_THR 11.0f

__device__ __forceinline__ unsigned short f2bf(float f) {
  unsigned u = __float_as_uint(f);
  unsigned r = u + 0x7FFFu + ((u >> 16) & 1u);
  return (unsigned short)(r >> 16);
}
__device__ __forceinline__ float bf2f(unsigned short b) {
  return __uint_as_float(((unsigned)b) << 16);
}
__device__ __forceinline__ unsigned pack_bf2(float a, float b) {
  return ((unsigned)f2bf(a)) | (((unsigned)f2bf(b)) << 16);
}
__device__ __forceinline__ void gload16(const void* g, void* l) {
  __builtin_amdgcn_global_load_lds((const __attribute__((address_space(1))) void*)g,
                                   (__attribute__((address_space(3))) void*)l, 16, 0, 0);
}

// ---------------- elementwise f32 -> bf16 ----------------
__global__ __launch_bounds__(256) void cvt_bf16_kernel(const float* __restrict__ src,
                                                       ushort* __restrict__ dst, int n) {
  int i = (blockIdx.x * 256 + threadIdx.x) * 4;
  if (i + 3 < n) {
    float4 v = *(const float4*)(src + i);
    ushort4 o;
    o.x = f2bf(v.x); o.y = f2bf(v.y); o.z = f2bf(v.z); o.w = f2bf(v.w);
    *(ushort4*)(dst + i) = o;
  }
}

// ---------------- transpose + cast: src[R][C] f32 -> dst[C][R] bf16 ----------------
__global__ __launch_bounds__(256) void transpose_cvt_kernel(const float* __restrict__ src,
                                                            ushort* __restrict__ dst,
                                                            int R, int C) {
  __shared__ float tile[32][33];
  int tx = threadIdx.x & 31, ty = threadIdx.x >> 5;
  int c0 = blockIdx.x * 32, r0 = blockIdx.y * 32;
#pragma unroll
  for (int i = 0; i < 32; i += 8)
    tile[ty + i][tx] = src[(size_t)(r0 + ty + i) * C + c0 + tx];
  __syncthreads();
#pragma unroll
  for (int i = 0; i < 32; i += 8)
    dst[(size_t)(c0 + ty + i) * R + r0 + tx] = f2bf(tile[tx][ty + i]);
}

// ---------------- GEMM: C[M][N] = A[M][K] * Bt[N][K]^T + bias ----------------
// global_load_lds staging (m97 structure), linear LDS [128][64].
// MODE 0: scatter q (pre-scaled)/k head-major + v transposed.  MODE 1: f32 out.
#define BK 64

template <int MODE>
__global__ __launch_bounds__(256) void gemm_bt_kernel(const ushort* __restrict__ A,
                                                      const ushort* __restrict__ Bt,
                                                      const float* __restrict__ bias,
                                                      ushort* __restrict__ o16,
                                                      float* __restrict__ o32,
                                                      int N, int K) {
  __shared__ ushort As[128 * 64];
  __shared__ ushort Bs[128 * 64];
  int tid = threadIdx.x, w = tid >> 6, lane = tid & 63;
  int wr = w >> 1, wc = w & 1;
  int l15 = lane & 15, g = lane >> 4;
  int bm = blockIdx.y * 128, bn = blockIdx.x * 128;
  f32x4 acc[4][4];
#pragma unroll
  for (int m = 0; m < 4; ++m)
#pragma unroll
    for (int n = 0; n < 4; ++n) acc[m][n] = (f32x4){0.f, 0.f, 0.f, 0.f};

  int srow = lane >> 3;        // 0..7 within 8-row chunk
  int scol = (lane & 7) * 8;   // 16B per lane

  for (int k0 = 0; k0 < K; k0 += BK) {
    __syncthreads();   // previous tile fully consumed
#pragma unroll
    for (int i = 0; i < 4; ++i) {
      int ch = w * 4 + i;                 // 16 chunks of 8 rows
      int row = ch * 8 + srow;
      gload16(A + (size_t)(bm + row) * K + k0 + scol, &As[ch * 512]);
      gload16(Bt + (size_t)(bn + row) * K + k0 + scol, &Bs[ch * 512]);
    }
    __syncthreads();   // compiler drains vmcnt before barrier
    short8 a[4][2], b[4][2];
#pragma unroll
    for (int m = 0; m < 4; ++m)
#pragma unroll
      for (int t = 0; t < 2; ++t)
        a[m][t] = *(const short8*)&As[(wr * 64 + m * 16 + l15) * 64 + t * 32 + g * 8];
#pragma unroll
    for (int n = 0; n < 4; ++n)
#pragma unroll
      for (int t = 0; t < 2; ++t)
        b[n][t] = *(const short8*)&Bs[(wc * 64 + n * 16 + l15) * 64 + t * 32 + g * 8];
#pragma unroll
    for (int m = 0; m < 4; ++m)
#pragma unroll
      for (int n = 0; n < 4; ++n)
#pragma unroll
        for (int t = 0; t < 2; ++t)
          acc[m][n] = __builtin_amdgcn_mfma_f32_16x16x32_bf16(a[m][t], b[n][t], acc[m][n], 0, 0, 0);
  }

#pragma unroll
  for (int m = 0; m < 4; ++m) {
    int rbase = bm + wr * 64 + m * 16 + g * 4;
#pragma unroll
    for (int n = 0; n < 4; ++n) {
      int c = bn + wc * 64 + n * 16 + l15;
      float bv = bias[c];
      if (MODE == 0) {
        int which = c >> 10, cc = c & 1023, hh = cc >> 6, dcol = cc & 63;
        if (which == 2) {
          ushort4 o;
          o.x = f2bf(acc[m][n][0] + bv);
          o.y = f2bf(acc[m][n][1] + bv);
          o.z = f2bf(acc[m][n][2] + bv);
          o.w = f2bf(acc[m][n][3] + bv);
          *(ushort4*)&o16[8388608u + (size_t)hh * (DHEAD * (size_t)S_LEN) +
                          (size_t)dcol * S_LEN + rbase] = o;
        } else {
          float qs = (which == 0) ? QSCALE : 1.0f;
          ushort* dst = o16 + (size_t)which * 4194304u +
                        (size_t)hh * (S_LEN * DHEAD) + dcol;
#pragma unroll
          for (int j = 0; j < 4; ++j)
            dst[(size_t)(rbase + j) * DHEAD] = f2bf((acc[m][n][j] + bv) * qs);
        }
      } else {
#pragma unroll
        for (int j = 0; j < 4; ++j)
          o32[(size_t)(rbase + j) * N + c] = acc[m][n][j] + bv;
      }
    }
  }
}

// ---------------- causal flash attention, swapped-QK lane-local softmax ----------------
// Q (pre-scaled), K: [H][S][64].  Vt: [H][64][S].  Split-KV x2, pair-balanced.
// Swapped QK^T -> S^T: each lane owns q-row (l15), keys ct*16+g*4+j in regs.
// PV via mfma_f32_16x16x16bf16_1k: S^T reg layout IS the B-frag layout -> no exchange.
#define LDT 72

__global__ __launch_bounds__(256) void attn_kernel(const ushort* __restrict__ Q,
                                                   const ushort* __restrict__ Kg,
                                                   const ushort* __restrict__ Vtg,
                                                   ushort* __restrict__ P0,
                                                   ushort* __restrict__ P1,
                                                   float2* __restrict__ ml) {
  __shared__ ushort Ks[64 * LDT];
  __shared__ ushort Vs[64 * LDT];
  int bid = blockIdx.x;
  int c = bid & 1, p = (bid >> 1) & 31, h = bid >> 6;
  int tid = threadIdx.x, w = tid >> 6, lane = tid & 63;
  int l15 = lane & 15, g = lane >> 4;
  const ushort* qh = Q + (size_t)h * (S_LEN * DHEAD);
  const ushort* kh = Kg + (size_t)h * (S_LEN * DHEAD);
  const ushort* vh = Vtg + (size_t)h * (DHEAD * (size_t)S_LEN);
  int sr = tid >> 2;
  int scc = (tid & 3) * 16;
  ushort* Pc = c ? P1 : P0;

#pragma unroll 1
  for (int half = 0; half < 2; ++half) {
    int qt = half ? (63 - p) : p;
    int q0 = qt * 64;

    if (c > qt) {  // empty chunk (only qt=0,c=1): zero partial
      int row = q0 + (tid >> 2);
      int cb = (tid & 3) * 16;
      short8 z = (short8){0, 0, 0, 0, 0, 0, 0, 0};
      *(short8*)&Pc[(size_t)row * D_EMB + h * DHEAD + cb] = z;
      *(short8*)&Pc[(size_t)row * D_EMB + h * DHEAD + cb + 8] = z;
      if (tid < 64)
        ml[(size_t)(c * NH + h) * S_LEN + q0 + tid] = make_float2(-1e30f, 0.f);
      continue;
    }

    int qrow = q0 + w * 16 + l15;   // this lane's q row
    short8 aq[2];
#pragma unroll
    for (int t = 0; t < 2; ++t)
      aq[t] = *(const short8*)&qh[(size_t)qrow * DHEAD + t * 32 + g * 8];

    f32x4 acc_o[4];
#pragma unroll
    for (int dt = 0; dt < 4; ++dt) acc_o[dt] = (f32x4){0.f, 0.f, 0.f, 0.f};
    float m = -1e30f, l = 0.f;

    // prologue: stage tile c
    {
      int kv0 = c * 64;
      short8 ka = *(const short8*)&kh[(size_t)(kv0 + sr) * DHEAD + scc];
      short8 kb = *(const short8*)&kh[(size_t)(kv0 + sr) * DHEAD + scc + 8];
      short8 va = *(const short8*)&vh[(size_t)sr * S_LEN + kv0 + scc];
      short8 vb = *(const short8*)&vh[(size_t)sr * S_LEN + kv0 + scc + 8];
      __syncthreads();
      *(short8*)&Ks[sr * LDT + scc] = ka;
      *(short8*)&Ks[sr * LDT + scc + 8] = kb;
      *(short8*)&Vs[sr * LDT + scc] = va;
      *(short8*)&Vs[sr * LDT + scc + 8] = vb;
      __syncthreads();
    }

    for (int it = c; it <= qt; it += 2) {
      int kv0 = it * 64;
      bool more = (it + 2 <= qt);
      short8 nka, nkb, nva, nvb;
      if (more) {
        int kv1 = kv0 + 128;
        nka = *(const short8*)&kh[(size_t)(kv1 + sr) * DHEAD + scc];
        nkb = *(const short8*)&kh[(size_t)(kv1 + sr) * DHEAD + scc + 8];
        nva = *(const short8*)&vh[(size_t)sr * S_LEN + kv1 + scc];
        nvb = *(const short8*)&vh[(size_t)sr * S_LEN + kv1 + scc + 8];
      }

      // swapped QK^T: accs[ct] = S^T[key=ct*16+g*4+j][q=l15] (log2 units)
      f32x4 accs[4];
#pragma unroll
      for (int ct = 0; ct < 4; ++ct) accs[ct] = (f32x4){0.f, 0.f, 0.f, 0.f};
#pragma unroll
      for (int ct = 0; ct < 4; ++ct)
#pragma unroll
        for (int t = 0; t < 2; ++t) {
          short8 kf = *(const short8*)&Ks[(ct * 16 + l15) * LDT + t * 32 + g * 8];
          accs[ct] = __builtin_amdgcn_mfma_f32_16x16x32_bf16(kf, aq[t], accs[ct], 0, 0, 0);
        }

      if (it == qt) {  // diagonal tile: causal mask
#pragma unroll
        for (int ct = 0; ct < 4; ++ct) {
          int kbase = kv0 + ct * 16 + g * 4;
#pragma unroll
          for (int j = 0; j < 4; ++j)
            if (kbase + j > qrow) accs[ct][j] = -1e30f;
        }
      }

      // lane-local max + 2-shuffle cross-g reduce
      float pm = accs[0][0];
#pragma unroll
      for (int ct = 0; ct < 4; ++ct)
#pragma unroll
        for (int j = 0; j < 4; ++j) pm = fmaxf(pm, accs[ct][j]);
      pm = fmaxf(pm, __shfl_xor(pm, 16));
      pm = fmaxf(pm, __shfl_xor(pm, 32));

      if (!__all(pm <= m + DEFER_THR)) {
        float mnew = fmaxf(m, pm);
        float corr = __builtin_amdgcn_exp2f(m - mnew);
        l *= corr; m = mnew;
#pragma unroll
        for (int dt = 0; dt < 4; ++dt)
#pragma unroll
          for (int j = 0; j < 4; ++j) acc_o[dt][j] *= corr;
      }

      float rs = 0.f;
      short4v pk4[4];
#pragma unroll
      for (int ct = 0; ct < 4; ++ct) {
        float p0 = __builtin_amdgcn_exp2f(accs[ct][0] - m);
        float p1 = __builtin_amdgcn_exp2f(accs[ct][1] - m);
        float p2 = __builtin_amdgcn_exp2f(accs[ct][2] - m);
        float p3 = __builtin_amdgcn_exp2f(accs[ct][3] - m);
        rs += (p0 + p1) + (p2 + p3);
        union { unsigned u[2]; short4v v; } pu;
        pu.u[0] = pack_bf2(p0, p1);
        pu.u[1] = pack_bf2(p2, p3);
        pk4[ct] = pu.v;
      }
      rs += __shfl_xor(rs, 16);
      rs += __shfl_xor(rs, 32);
      l += rs;

      // swapped PV: acc_o[dt] = O^T[d=dt*16+g*4+j][q=l15]
#pragma unroll
      for (int dt = 0; dt < 4; ++dt) {
        int rb = (dt * 16 + l15) * LDT + g * 4;
#pragma unroll
        for (int ct = 0; ct < 4; ++ct) {
          short4v vf = *(const short4v*)&Vs[rb + ct * 16];
          acc_o[dt] = __builtin_amdgcn_mfma_f32_16x16x16bf16_1k(vf, pk4[ct], acc_o[dt], 0, 0, 0);
        }
      }

      __syncthreads();
      if (more) {
        *(short8*)&Ks[sr * LDT + scc] = nka;
        *(short8*)&Ks[sr * LDT + scc + 8] = nkb;
        *(short8*)&Vs[sr * LDT + scc] = nva;
        *(short8*)&Vs[sr * LDT + scc + 8] = nvb;
        __syncthreads();
      }
    }

    // epilogue: normalized partial (O^T regs -> row-major store) + (m,l)
    float rl = (l > 0.f) ? 1.f / l : 0.f;
#pragma unroll
    for (int dt = 0; dt < 4; ++dt) {
      ushort4 o;
      o.x = f2bf(acc_o[dt][0] * rl);
      o.y = f2bf(acc_o[dt][1] * rl);
      o.z = f2bf(acc_o[dt][2] * rl);
      o.w = f2bf(acc_o[dt][3] * rl);
      *(ushort4*)&Pc[(size_t)qrow * D_EMB + h * DHEAD + dt * 16 + g * 4] = o;
    }
    if (g == 0)
      ml[(size_t)(c * NH + h) * S_LEN + qrow] = make_float2(m, l);
  }
}

// ---------------- combine the two KV-chunk partials ----------------
__global__ __launch_bounds__(256) void combine_kernel(const ushort* __restrict__ P0,
                                                      const ushort* __restrict__ P1,
                                                      const float2* __restrict__ ml,
                                                      ushort* __restrict__ Out) {
  int idx = blockIdx.x * 256 + threadIdx.x;
  int row = idx >> 7;
  int cb = (idx & 127) * 8;
  int h = cb >> 6;
  float2 e0 = ml[(size_t)h * S_LEN + row];
  float2 e1 = ml[(size_t)(NH + h) * S_LEN + row];
  float mm = fmaxf(e0.x, e1.x);
  float w0 = e0.y * __builtin_amdgcn_exp2f(e0.x - mm);
  float w1 = e1.y * __builtin_amdgcn_exp2f(e1.x - mm);
  float inv = 1.f / (w0 + w1);
  w0 *= inv; w1 *= inv;
  size_t base = (size_t)row * D_EMB + cb;
  short8 a = *(const short8*)&P0[base];
  short8 b = *(const short8*)&P1[base];
  short8 o;
#pragma unroll
  for (int i = 0; i < 8; ++i) {
    float fv = w0 * bf2f((unsigned short)a[i]) + w1 * bf2f((unsigned short)b[i]);
    o[i] = (short)f2bf(fv);
  }
  *(short8*)&Out[base] = o;
}

extern "C" void kernel_launch(void* const* d_in, const int* in_sizes, int n_in,
                              void* d_out, int out_size, void* d_ws, size_t ws_size,
                              hipStream_t stream) {
  const float* x = (const float*)d_in[0];
  const float* W_in = (const float*)d_in[1];
  const float* b_in = (const float*)d_in[2];
  const float* W_out = (const float*)d_in[3];
  const float* b_out = (const float*)d_in[4];
  float* out = (float*)d_out;
  ushort* ws = (ushort*)d_ws;

  ushort* P0 = ws + OFF_ATTN;
  ushort* P1 = ws + OFF_XB;
  float2* ml = (float2*)(ws + OFF_WINT);

  cvt_bf16_kernel<<<4096, 256, 0, stream>>>(x, ws + OFF_XB, S_LEN * D_EMB);
  transpose_cvt_kernel<<<dim3(N3 / 32, D_EMB / 32), 256, 0, stream>>>(W_in, ws + OFF_WINT, D_EMB, N3);
  transpose_cvt_kernel<<<dim3(D_EMB / 32, D_EMB / 32), 256, 0, stream>>>(W_out, ws + OFF_WOUTT, D_EMB, D_EMB);
  gemm_bt_kernel<0><<<dim3(N3 / 128, S_LEN / 128), 256, 0, stream>>>(
      ws + OFF_XB, ws + OFF_WINT, b_in, ws + OFF_Q, nullptr, N3, D_EMB);
  attn_kernel<<<NH * 64, 256, 0, stream>>>(
      ws + OFF_Q, ws + OFF_Q + 4194304u, ws + OFF_Q + 8388608u, P0, P1, ml);
  combine_kernel<<<(S_LEN * D_EMB / 8) / 256, 256, 0, stream>>>(P0, P1, ml, P0);
  gemm_bt_kernel<1><<<dim3(D_EMB / 128, S_LEN / 128), 256, 0, stream>>>(
      P0, ws + OFF_WOUTT, b_out, nullptr, out, D_EMB, D_EMB);
}

// Round 5
// 191.894 us; speedup vs baseline: 1.1997x; 1.0581x over previous
//
#include <hip/hip_runtime.h>
#include <stdint.h>

#define S_LEN 4096
#define D_EMB 1024
#define NH 16
#define DHEAD 64
#define N3 3072

typedef __attribute__((ext_vector_type(8))) short short8;
typedef __attribute__((ext_vector_type(4))) short short4v;
typedef __attribute__((ext_vector_type(4))) float f32x4;

// workspace layout (ushort elements)
#define OFF_XB    0u         // x bf16 [4096][1024]
#define OFF_WINT  4194304u   // W_in^T bf16
#define OFF_WOUTT 7340032u   // W_out^T bf16 (live until gemm2)
#define OFF_Q     8388608u   // q [H][S][64], k [H][S][64], v^T [H][64][S]
#define OFF_ATTN  20971520u  // attn out [4096][1024] bf16

// 0.125 (1/sqrt(64)) * log2(e)
#define QSCALE 0.1803368801111204f
#define DEFER_THR 11.0f

__device__ __forceinline__ unsigned short f2bf(float f) {
  unsigned u = __float_as_uint(f);
  unsigned r = u + 0x7FFFu + ((u >> 16) & 1u);
  return (unsigned short)(r >> 16);
}
__device__ __forceinline__ unsigned cvtpk_bf16(float lo, float hi) {
  unsigned r;
  asm("v_cvt_pk_bf16_f32 %0, %1, %2" : "=v"(r) : "v"(lo), "v"(hi));
  return r;
}
__device__ __forceinline__ void gload16(const void* g, void* l) {
  __builtin_amdgcn_global_load_lds((const __attribute__((address_space(1))) void*)g,
                                   (__attribute__((address_space(3))) void*)l, 16, 0, 0);
}

// ---------------- elementwise f32 -> bf16 ----------------
__global__ __launch_bounds__(256) void cvt_bf16_kernel(const float* __restrict__ src,
                                                       ushort* __restrict__ dst, int n) {
  int i = (blockIdx.x * 256 + threadIdx.x) * 4;
  if (i + 3 < n) {
    float4 v = *(const float4*)(src + i);
    ushort4 o;
    o.x = f2bf(v.x); o.y = f2bf(v.y); o.z = f2bf(v.z); o.w = f2bf(v.w);
    *(ushort4*)(dst + i) = o;
  }
}

// ---------------- transpose + cast: src[R][C] f32 -> dst[C][R] bf16 ----------------
__global__ __launch_bounds__(256) void transpose_cvt_kernel(const float* __restrict__ src,
                                                            ushort* __restrict__ dst,
                                                            int R, int C) {
  __shared__ float tile[32][33];
  int tx = threadIdx.x & 31, ty = threadIdx.x >> 5;
  int c0 = blockIdx.x * 32, r0 = blockIdx.y * 32;
#pragma unroll
  for (int i = 0; i < 32; i += 8)
    tile[ty + i][tx] = src[(size_t)(r0 + ty + i) * C + c0 + tx];
  __syncthreads();
#pragma unroll
  for (int i = 0; i < 32; i += 8)
    dst[(size_t)(c0 + ty + i) * R + r0 + tx] = f2bf(tile[tx][ty + i]);
}

// ---------------- GEMM: C[M][N] = A[M][K] * Bt[N][K]^T + bias ----------------
// global_load_lds staging, linear LDS [128][64], XCD-swizzled block order.
// MODE 0: scatter q (pre-scaled)/k head-major + v transposed.  MODE 1: f32 out.
#define BK 64

template <int MODE>
__global__ __launch_bounds__(256) void gemm_bt_kernel(const ushort* __restrict__ A,
                                                      const ushort* __restrict__ Bt,
                                                      const float* __restrict__ bias,
                                                      ushort* __restrict__ o16,
                                                      float* __restrict__ o32,
                                                      int N, int K) {
  __shared__ ushort As[128 * 64];
  __shared__ ushort Bs[128 * 64];
  int tid = threadIdx.x, w = tid >> 6, lane = tid & 63;
  int wr = w >> 1, wc = w & 1;
  int l15 = lane & 15, g = lane >> 4;
  // XCD-bijective swizzle (grid size % 8 == 0 for both GEMMs)
  int gx = gridDim.x;
  int id = blockIdx.y * gx + blockIdx.x;
  int q8 = (gx * gridDim.y) >> 3;
  int id2 = (id & 7) * q8 + (id >> 3);
  int bm = (id2 / gx) * 128, bn = (id2 % gx) * 128;
  f32x4 acc[4][4];
#pragma unroll
  for (int m = 0; m < 4; ++m)
#pragma unroll
    for (int n = 0; n < 4; ++n) acc[m][n] = (f32x4){0.f, 0.f, 0.f, 0.f};

  int srow = lane >> 3;        // 0..7 within 8-row chunk
  int scol = (lane & 7) * 8;   // 16B per lane

  for (int k0 = 0; k0 < K; k0 += BK) {
    __syncthreads();
#pragma unroll
    for (int i = 0; i < 4; ++i) {
      int ch = w * 4 + i;
      int row = ch * 8 + srow;
      gload16(A + (size_t)(bm + row) * K + k0 + scol, &As[ch * 512]);
      gload16(Bt + (size_t)(bn + row) * K + k0 + scol, &Bs[ch * 512]);
    }
    __syncthreads();
    short8 a[4][2], b[4][2];
#pragma unroll
    for (int m = 0; m < 4; ++m)
#pragma unroll
      for (int t = 0; t < 2; ++t)
        a[m][t] = *(const short8*)&As[(wr * 64 + m * 16 + l15) * 64 + t * 32 + g * 8];
#pragma unroll
    for (int n = 0; n < 4; ++n)
#pragma unroll
      for (int t = 0; t < 2; ++t)
        b[n][t] = *(const short8*)&Bs[(wc * 64 + n * 16 + l15) * 64 + t * 32 + g * 8];
#pragma unroll
    for (int m = 0; m < 4; ++m)
#pragma unroll
      for (int n = 0; n < 4; ++n)
#pragma unroll
        for (int t = 0; t < 2; ++t)
          acc[m][n] = __builtin_amdgcn_mfma_f32_16x16x32_bf16(a[m][t], b[n][t], acc[m][n], 0, 0, 0);
  }

#pragma unroll
  for (int m = 0; m < 4; ++m) {
    int rbase = bm + wr * 64 + m * 16 + g * 4;
#pragma unroll
    for (int n = 0; n < 4; ++n) {
      int c = bn + wc * 64 + n * 16 + l15;
      float bv = bias[c];
      if (MODE == 0) {
        int which = c >> 10, cc = c & 1023, hh = cc >> 6, dcol = cc & 63;
        if (which == 2) {
          ushort4 o;
          o.x = f2bf(acc[m][n][0] + bv);
          o.y = f2bf(acc[m][n][1] + bv);
          o.z = f2bf(acc[m][n][2] + bv);
          o.w = f2bf(acc[m][n][3] + bv);
          *(ushort4*)&o16[8388608u + (size_t)hh * (DHEAD * (size_t)S_LEN) +
                          (size_t)dcol * S_LEN + rbase] = o;
        } else {
          float qs = (which == 0) ? QSCALE : 1.0f;
          ushort* dst = o16 + (size_t)which * 4194304u +
                        (size_t)hh * (S_LEN * DHEAD) + dcol;
#pragma unroll
          for (int j = 0; j < 4; ++j)
            dst[(size_t)(rbase + j) * DHEAD] = f2bf((acc[m][n][j] + bv) * qs);
        }
      } else {
#pragma unroll
        for (int j = 0; j < 4; ++j)
          o32[(size_t)(rbase + j) * N + c] = acc[m][n][j] + bv;
      }
    }
  }
}

// ---------------- causal flash attention ----------------
// Q (pre-scaled, log2 units), K: [H][S][64].  Vt: [H][64][S].  O: [S][1024] bf16.
// QBLK=128 (8 waves), KVBLK=64, double-buffered LDS, ONE barrier per tile.
// Swapped QK^T: lane owns q-row l15, keys ct*16+g*4+j in regs; PV via 16x16x16_1k.
// Grid 512 blocks, longest q-tile first for backfill balance.
#define LDT 72

__global__ __launch_bounds__(512) void attn_kernel(const ushort* __restrict__ Q,
                                                   const ushort* __restrict__ Kg,
                                                   const ushort* __restrict__ Vtg,
                                                   ushort* __restrict__ O) {
  __shared__ ushort Ks[2][64 * LDT];
  __shared__ ushort Vs[2][64 * LDT];
  int bid = blockIdx.x;
  int h = bid & 15, qt = 31 - (bid >> 4);   // longest-first dispatch
  int q0 = qt * 128;
  int tid = threadIdx.x, w = tid >> 6, lane = tid & 63;
  int l15 = lane & 15, g = lane >> 4;
  const ushort* qh = Q + (size_t)h * (S_LEN * DHEAD);
  const ushort* kh = Kg + (size_t)h * (S_LEN * DHEAD);
  const ushort* vh = Vtg + (size_t)h * (DHEAD * (size_t)S_LEN);
  int sr = tid >> 3;           // 0..63 staging row
  int scc = (tid & 7) * 8;     // 16B per thread

  int qrow = q0 + w * 16 + l15;   // this lane's q row
  short8 aq[2];
#pragma unroll
  for (int t = 0; t < 2; ++t)
    aq[t] = *(const short8*)&qh[(size_t)qrow * DHEAD + t * 32 + g * 8];

  f32x4 acc_o[4];
#pragma unroll
  for (int dt = 0; dt < 4; ++dt) acc_o[dt] = (f32x4){0.f, 0.f, 0.f, 0.f};
  float m = -1e30f, l = 0.f;
  int last = 2 * qt + 1;

  // prologue: stage tile 0 into buf0; issue tile 1 loads into regs
  {
    short8 ka = *(const short8*)&kh[(size_t)sr * DHEAD + scc];
    short8 va = *(const short8*)&vh[(size_t)sr * S_LEN + scc];
    *(short8*)&Ks[0][sr * LDT + scc] = ka;
    *(short8*)&Vs[0][sr * LDT + scc] = va;
  }
  short8 nk, nv;
  {  // last >= 1 always
    nk = *(const short8*)&kh[(size_t)(64 + sr) * DHEAD + scc];
    nv = *(const short8*)&vh[(size_t)sr * S_LEN + 64 + scc];
  }
  __syncthreads();
  int cur = 0;

  for (int it = 0; it <= last; ++it) {
    int kv0 = it * 64;
    bool more = (it < last);
    const ushort* Kc = Ks[cur];
    const ushort* Vc = Vs[cur];

    // swapped QK^T: accs[ct][j] = S^T[key = kv0+ct*16+g*4+j][q = l15-row of this wave]
    f32x4 accs[4];
#pragma unroll
    for (int ct = 0; ct < 4; ++ct) accs[ct] = (f32x4){0.f, 0.f, 0.f, 0.f};
    __builtin_amdgcn_s_setprio(1);
#pragma unroll
    for (int ct = 0; ct < 4; ++ct)
#pragma unroll
      for (int t = 0; t < 2; ++t) {
        short8 kf = *(const short8*)&Kc[(ct * 16 + l15) * LDT + t * 32 + g * 8];
        accs[ct] = __builtin_amdgcn_mfma_f32_16x16x32_bf16(kf, aq[t], accs[ct], 0, 0, 0);
      }
    __builtin_amdgcn_s_setprio(0);

    if (it >= 2 * qt) {  // diagonal band: causal mask
#pragma unroll
      for (int ct = 0; ct < 4; ++ct) {
        int kbase = kv0 + ct * 16 + g * 4;
#pragma unroll
        for (int j = 0; j < 4; ++j)
          if (kbase + j > qrow) accs[ct][j] = -1e30f;
      }
    }

    // lane-local max + 2-shuffle cross-group reduce
    float pm = accs[0][0];
#pragma unroll
    for (int ct = 0; ct < 4; ++ct)
#pragma unroll
      for (int j = 0; j < 4; ++j) pm = fmaxf(pm, accs[ct][j]);
    pm = fmaxf(pm, __shfl_xor(pm, 16));
    pm = fmaxf(pm, __shfl_xor(pm, 32));

    if (!__all(pm <= m + DEFER_THR)) {
      float mnew = fmaxf(m, pm);
      float corr = __builtin_amdgcn_exp2f(m - mnew);
      l *= corr; m = mnew;
#pragma unroll
      for (int dt = 0; dt < 4; ++dt)
#pragma unroll
        for (int j = 0; j < 4; ++j) acc_o[dt][j] *= corr;
    }

    float rs = 0.f;
    short4v pk4[4];
#pragma unroll
    for (int ct = 0; ct < 4; ++ct) {
      float p0 = __builtin_amdgcn_exp2f(accs[ct][0] - m);
      float p1 = __builtin_amdgcn_exp2f(accs[ct][1] - m);
      float p2 = __builtin_amdgcn_exp2f(accs[ct][2] - m);
      float p3 = __builtin_amdgcn_exp2f(accs[ct][3] - m);
      rs += (p0 + p1) + (p2 + p3);
      union { unsigned u[2]; short4v v; } pu;
      pu.u[0] = cvtpk_bf16(p0, p1);
      pu.u[1] = cvtpk_bf16(p2, p3);
      pk4[ct] = pu.v;
    }
    rs += __shfl_xor(rs, 16);
    rs += __shfl_xor(rs, 32);
    l += rs;

    // swapped PV: acc_o[dt][j] = O^T[d = dt*16+g*4+j][q = l15]
    __builtin_amdgcn_s_setprio(1);
#pragma unroll
    for (int dt = 0; dt < 4; ++dt) {
      int rb = (dt * 16 + l15) * LDT + g * 4;
#pragma unroll
      for (int ct = 0; ct < 4; ++ct) {
        short4v vf = *(const short4v*)&Vc[rb + ct * 16];
        acc_o[dt] = __builtin_amdgcn_mfma_f32_16x16x16bf16_1k(vf, pk4[ct], acc_o[dt], 0, 0, 0);
      }
    }
    __builtin_amdgcn_s_setprio(0);

    // write next tile (regs -> other buffer), issue loads for tile it+2
    if (more) {
      *(short8*)&Ks[cur ^ 1][sr * LDT + scc] = nk;
      *(short8*)&Vs[cur ^ 1][sr * LDT + scc] = nv;
      if (it + 2 <= last) {
        int kv2 = kv0 + 128;
        nk = *(const short8*)&kh[(size_t)(kv2 + sr) * DHEAD + scc];
        nv = *(const short8*)&vh[(size_t)sr * S_LEN + kv2 + scc];
      }
    }
    __syncthreads();
    cur ^= 1;
  }

  // epilogue: normalize + store (O^T regs -> row-major)
  float rl = (l > 0.f) ? 1.f / l : 0.f;
#pragma unroll
  for (int dt = 0; dt < 4; ++dt) {
    ushort4 o;
    o.x = f2bf(acc_o[dt][0] * rl);
    o.y = f2bf(acc_o[dt][1] * rl);
    o.z = f2bf(acc_o[dt][2] * rl);
    o.w = f2bf(acc_o[dt][3] * rl);
    *(ushort4*)&O[(size_t)qrow * D_EMB + h * DHEAD + dt * 16 + g * 4] = o;
  }
}

extern "C" void kernel_launch(void* const* d_in, const int* in_sizes, int n_in,
                              void* d_out, int out_size, void* d_ws, size_t ws_size,
                              hipStream_t stream) {
  const float* x = (const float*)d_in[0];
  const float* W_in = (const float*)d_in[1];
  const float* b_in = (const float*)d_in[2];
  const float* W_out = (const float*)d_in[3];
  const float* b_out = (const float*)d_in[4];
  float* out = (float*)d_out;
  ushort* ws = (ushort*)d_ws;

  cvt_bf16_kernel<<<4096, 256, 0, stream>>>(x, ws + OFF_XB, S_LEN * D_EMB);
  transpose_cvt_kernel<<<dim3(N3 / 32, D_EMB / 32), 256, 0, stream>>>(W_in, ws + OFF_WINT, D_EMB, N3);
  transpose_cvt_kernel<<<dim3(D_EMB / 32, D_EMB / 32), 256, 0, stream>>>(W_out, ws + OFF_WOUTT, D_EMB, D_EMB);
  gemm_bt_kernel<0><<<dim3(N3 / 128, S_LEN / 128), 256, 0, stream>>>(
      ws + OFF_XB, ws + OFF_WINT, b_in, ws + OFF_Q, nullptr, N3, D_EMB);
  attn_kernel<<<512, 512, 0, stream>>>(
      ws + OFF_Q, ws + OFF_Q + 4194304u, ws + OFF_Q + 8388608u, ws + OFF_ATTN);
  gemm_bt_kernel<1><<<dim3(D_EMB / 128, S_LEN / 128), 256, 0, stream>>>(
      ws + OFF_ATTN, ws + OFF_WOUTT, b_out, nullptr, out, D_EMB, D_EMB);
}

// Round 6
// 169.879 us; speedup vs baseline: 1.3552x; 1.1296x over previous
//
#include <hip/hip_runtime.h>
#include <stdint.h>

#define S_LEN 4096
#define D_EMB 1024
#define NH 16
#define DHEAD 64
#define N3 3072

typedef __attribute__((ext_vector_type(8))) short short8;
typedef __attribute__((ext_vector_type(4))) short short4v;
typedef __attribute__((ext_vector_type(4))) float f32x4;

// workspace layout (ushort elements)
#define OFF_XB    0u         // x bf16 [4096][1024]
#define OFF_WINT  4194304u   // W_in^T bf16
#define OFF_WOUTT 7340032u   // W_out^T bf16 (live until gemm2)
#define OFF_Q     8388608u   // q [H][S][64], k [H][S][64], v^T [H][64][S]
#define OFF_ATTN  20971520u  // attn out [4096][1024] bf16

// 0.125 (1/sqrt(64)) * log2(e)
#define QSCALE 0.1803368801111204f
#define DEFER_THR 11.0f

__device__ __forceinline__ unsigned short f2bf(float f) {
  unsigned u = __float_as_uint(f);
  unsigned r = u + 0x7FFFu + ((u >> 16) & 1u);
  return (unsigned short)(r >> 16);
}
__device__ __forceinline__ unsigned cvtpk_bf16(float lo, float hi) {
  unsigned r;
  asm("v_cvt_pk_bf16_f32 %0, %1, %2" : "=v"(r) : "v"(lo), "v"(hi));
  return r;
}
__device__ __forceinline__ void gload16(const void* g, void* l) {
  __builtin_amdgcn_global_load_lds((const __attribute__((address_space(1))) void*)g,
                                   (__attribute__((address_space(3))) void*)l, 16, 0, 0);
}

// ---------------- elementwise f32 -> bf16 ----------------
__global__ __launch_bounds__(256) void cvt_bf16_kernel(const float* __restrict__ src,
                                                       ushort* __restrict__ dst, int n) {
  int i = (blockIdx.x * 256 + threadIdx.x) * 4;
  if (i + 3 < n) {
    float4 v = *(const float4*)(src + i);
    ushort4 o;
    o.x = f2bf(v.x); o.y = f2bf(v.y); o.z = f2bf(v.z); o.w = f2bf(v.w);
    *(ushort4*)(dst + i) = o;
  }
}

// ---------------- transpose + cast: src[R][C] f32 -> dst[C][R] bf16 ----------------
__global__ __launch_bounds__(256) void transpose_cvt_kernel(const float* __restrict__ src,
                                                            ushort* __restrict__ dst,
                                                            int R, int C) {
  __shared__ float tile[32][33];
  int tx = threadIdx.x & 31, ty = threadIdx.x >> 5;
  int c0 = blockIdx.x * 32, r0 = blockIdx.y * 32;
#pragma unroll
  for (int i = 0; i < 32; i += 8)
    tile[ty + i][tx] = src[(size_t)(r0 + ty + i) * C + c0 + tx];
  __syncthreads();
#pragma unroll
  for (int i = 0; i < 32; i += 8)
    dst[(size_t)(c0 + ty + i) * R + r0 + tx] = f2bf(tile[tx][ty + i]);
}

// ---------------- GEMM: C[M][N] = A[M][K] * Bt[N][K]^T + bias ----------------
// global_load_lds staging, linear LDS [128][64], XCD-swizzled block order.
// MODE 0: scatter q (pre-scaled)/k head-major + v transposed.  MODE 1: f32 out.
#define BK 64

template <int MODE>
__global__ __launch_bounds__(256) void gemm_bt_kernel(const ushort* __restrict__ A,
                                                      const ushort* __restrict__ Bt,
                                                      const float* __restrict__ bias,
                                                      ushort* __restrict__ o16,
                                                      float* __restrict__ o32,
                                                      int N, int K) {
  __shared__ ushort As[128 * 64];
  __shared__ ushort Bs[128 * 64];
  int tid = threadIdx.x, w = tid >> 6, lane = tid & 63;
  int wr = w >> 1, wc = w & 1;
  int l15 = lane & 15, g = lane >> 4;
  // XCD-bijective swizzle (grid size % 8 == 0 for both GEMMs)
  int gx = gridDim.x;
  int id = blockIdx.y * gx + blockIdx.x;
  int q8 = (gx * gridDim.y) >> 3;
  int id2 = (id & 7) * q8 + (id >> 3);
  int bm = (id2 / gx) * 128, bn = (id2 % gx) * 128;
  f32x4 acc[4][4];
#pragma unroll
  for (int m = 0; m < 4; ++m)
#pragma unroll
    for (int n = 0; n < 4; ++n) acc[m][n] = (f32x4){0.f, 0.f, 0.f, 0.f};

  int srow = lane >> 3;        // 0..7 within 8-row chunk
  int scol = (lane & 7) * 8;   // 16B per lane

  for (int k0 = 0; k0 < K; k0 += BK) {
    __syncthreads();
#pragma unroll
    for (int i = 0; i < 4; ++i) {
      int ch = w * 4 + i;
      int row = ch * 8 + srow;
      gload16(A + (size_t)(bm + row) * K + k0 + scol, &As[ch * 512]);
      gload16(Bt + (size_t)(bn + row) * K + k0 + scol, &Bs[ch * 512]);
    }
    __syncthreads();
    short8 a[4][2], b[4][2];
#pragma unroll
    for (int m = 0; m < 4; ++m)
#pragma unroll
      for (int t = 0; t < 2; ++t)
        a[m][t] = *(const short8*)&As[(wr * 64 + m * 16 + l15) * 64 + t * 32 + g * 8];
#pragma unroll
    for (int n = 0; n < 4; ++n)
#pragma unroll
      for (int t = 0; t < 2; ++t)
        b[n][t] = *(const short8*)&Bs[(wc * 64 + n * 16 + l15) * 64 + t * 32 + g * 8];
#pragma unroll
    for (int m = 0; m < 4; ++m)
#pragma unroll
      for (int n = 0; n < 4; ++n)
#pragma unroll
        for (int t = 0; t < 2; ++t)
          acc[m][n] = __builtin_amdgcn_mfma_f32_16x16x32_bf16(a[m][t], b[n][t], acc[m][n], 0, 0, 0);
  }

#pragma unroll
  for (int m = 0; m < 4; ++m) {
    int rbase = bm + wr * 64 + m * 16 + g * 4;
#pragma unroll
    for (int n = 0; n < 4; ++n) {
      int c = bn + wc * 64 + n * 16 + l15;
      float bv = bias[c];
      if (MODE == 0) {
        int which = c >> 10, cc = c & 1023, hh = cc >> 6, dcol = cc & 63;
        if (which == 2) {
          ushort4 o;
          o.x = f2bf(acc[m][n][0] + bv);
          o.y = f2bf(acc[m][n][1] + bv);
          o.z = f2bf(acc[m][n][2] + bv);
          o.w = f2bf(acc[m][n][3] + bv);
          *(ushort4*)&o16[8388608u + (size_t)hh * (DHEAD * (size_t)S_LEN) +
                          (size_t)dcol * S_LEN + rbase] = o;
        } else {
          float qs = (which == 0) ? QSCALE : 1.0f;
          ushort* dst = o16 + (size_t)which * 4194304u +
                        (size_t)hh * (S_LEN * DHEAD) + dcol;
#pragma unroll
          for (int j = 0; j < 4; ++j)
            dst[(size_t)(rbase + j) * DHEAD] = f2bf((acc[m][n][j] + bv) * qs);
        }
      } else {
#pragma unroll
        for (int j = 0; j < 4; ++j)
          o32[(size_t)(rbase + j) * N + c] = acc[m][n][j] + bv;
      }
    }
  }
}

// ---------------- causal flash attention ----------------
// Q (pre-scaled, log2 units), K: [H][S][64].  Vt: [H][64][S].  O: [S][1024] bf16.
// QBLK=128 (8 waves), KVBLK=64, double-buffered LDS, ONE barrier per tile.
// Swapped QK^T: lane owns q-row l15, keys ct*16+g*4+j in regs; PV via 16x16x16_1k.
// Grid 512: blocks i and i+256 pair to uniform 66 tile-units per CU (round-robin).
// Softmax: lane-local defer-max (reduce only in rare rescale branch); l is a
// per-lane partial reduced once in the epilogue -> zero shuffles per tile.
#define LDT 72

__global__ __launch_bounds__(512) void attn_kernel(const ushort* __restrict__ Q,
                                                   const ushort* __restrict__ Kg,
                                                   const ushort* __restrict__ Vtg,
                                                   ushort* __restrict__ O) {
  __shared__ ushort Ks[2][64 * LDT];
  __shared__ ushort Vs[2][64 * LDT];
  int bid = blockIdx.x;
  int h = bid & 15;
  int qt = (bid < 256) ? (31 - (bid >> 4)) : ((bid - 256) >> 4);
  int q0 = qt * 128;
  int tid = threadIdx.x, w = tid >> 6, lane = tid & 63;
  int l15 = lane & 15, g = lane >> 4;
  const ushort* qh = Q + (size_t)h * (S_LEN * DHEAD);
  const ushort* kh = Kg + (size_t)h * (S_LEN * DHEAD);
  const ushort* vh = Vtg + (size_t)h * (DHEAD * (size_t)S_LEN);
  int sr = tid >> 3;           // 0..63 staging row
  int scc = (tid & 7) * 8;     // 16B per thread

  int qrow = q0 + w * 16 + l15;   // this lane's q row
  short8 aq[2];
#pragma unroll
  for (int t = 0; t < 2; ++t)
    aq[t] = *(const short8*)&qh[(size_t)qrow * DHEAD + t * 32 + g * 8];

  f32x4 acc_o[4];
#pragma unroll
  for (int dt = 0; dt < 4; ++dt) acc_o[dt] = (f32x4){0.f, 0.f, 0.f, 0.f};
  float m = -1e30f, l = 0.f;   // l: per-lane partial (reduced in epilogue)
  int last = 2 * qt + 1;

  // prologue: stage tile 0 into buf0; issue tile 1 loads into regs
  {
    short8 ka = *(const short8*)&kh[(size_t)sr * DHEAD + scc];
    short8 va = *(const short8*)&vh[(size_t)sr * S_LEN + scc];
    *(short8*)&Ks[0][sr * LDT + scc] = ka;
    *(short8*)&Vs[0][sr * LDT + scc] = va;
  }
  short8 nk, nv;
  {  // last >= 1 always
    nk = *(const short8*)&kh[(size_t)(64 + sr) * DHEAD + scc];
    nv = *(const short8*)&vh[(size_t)sr * S_LEN + 64 + scc];
  }
  __syncthreads();
  int cur = 0;

  for (int it = 0; it <= last; ++it) {
    int kv0 = it * 64;
    bool more = (it < last);
    const ushort* Kc = Ks[cur];
    const ushort* Vc = Vs[cur];

    // swapped QK^T: accs[ct][j] = S^T[key = kv0+ct*16+g*4+j][q = l15-row of this wave]
    f32x4 accs[4];
#pragma unroll
    for (int ct = 0; ct < 4; ++ct) accs[ct] = (f32x4){0.f, 0.f, 0.f, 0.f};
    __builtin_amdgcn_s_setprio(1);
#pragma unroll
    for (int ct = 0; ct < 4; ++ct)
#pragma unroll
      for (int t = 0; t < 2; ++t) {
        short8 kf = *(const short8*)&Kc[(ct * 16 + l15) * LDT + t * 32 + g * 8];
        accs[ct] = __builtin_amdgcn_mfma_f32_16x16x32_bf16(kf, aq[t], accs[ct], 0, 0, 0);
      }
    __builtin_amdgcn_s_setprio(0);

    if (it >= 2 * qt) {  // diagonal band: causal mask
#pragma unroll
      for (int ct = 0; ct < 4; ++ct) {
        int kbase = kv0 + ct * 16 + g * 4;
#pragma unroll
        for (int j = 0; j < 4; ++j)
          if (kbase + j > qrow) accs[ct][j] = -1e30f;
      }
    }

    // lane-local max (tree, encourages v_max3)
    float m01 = fmaxf(fmaxf(accs[0][0], accs[0][1]), fmaxf(accs[0][2], accs[0][3]));
    float m11 = fmaxf(fmaxf(accs[1][0], accs[1][1]), fmaxf(accs[1][2], accs[1][3]));
    float m21 = fmaxf(fmaxf(accs[2][0], accs[2][1]), fmaxf(accs[2][2], accs[2][3]));
    float m31 = fmaxf(fmaxf(accs[3][0], accs[3][1]), fmaxf(accs[3][2], accs[3][3]));
    float pm = fmaxf(fmaxf(m01, m11), fmaxf(m21, m31));

    // defer-max: common path has NO cross-lane ops
    if (!__all(pm <= m + DEFER_THR)) {
      pm = fmaxf(pm, __shfl_xor(pm, 16));
      pm = fmaxf(pm, __shfl_xor(pm, 32));
      float mnew = fmaxf(m, pm);
      float corr = __builtin_amdgcn_exp2f(m - mnew);
      l *= corr; m = mnew;
#pragma unroll
      for (int dt = 0; dt < 4; ++dt)
#pragma unroll
        for (int j = 0; j < 4; ++j) acc_o[dt][j] *= corr;
    }

    float rs = 0.f;
    short4v pk4[4];
#pragma unroll
    for (int ct = 0; ct < 4; ++ct) {
      float p0 = __builtin_amdgcn_exp2f(accs[ct][0] - m);
      float p1 = __builtin_amdgcn_exp2f(accs[ct][1] - m);
      float p2 = __builtin_amdgcn_exp2f(accs[ct][2] - m);
      float p3 = __builtin_amdgcn_exp2f(accs[ct][3] - m);
      rs += (p0 + p1) + (p2 + p3);
      union { unsigned u[2]; short4v v; } pu;
      pu.u[0] = cvtpk_bf16(p0, p1);
      pu.u[1] = cvtpk_bf16(p2, p3);
      pk4[ct] = pu.v;
    }
    l += rs;   // per-lane partial

    // swapped PV: acc_o[dt][j] = O^T[d = dt*16+g*4+j][q = l15]
    __builtin_amdgcn_s_setprio(1);
#pragma unroll
    for (int dt = 0; dt < 4; ++dt) {
      int rb = (dt * 16 + l15) * LDT + g * 4;
#pragma unroll
      for (int ct = 0; ct < 4; ++ct) {
        short4v vf = *(const short4v*)&Vc[rb + ct * 16];
        acc_o[dt] = __builtin_amdgcn_mfma_f32_16x16x16bf16_1k(vf, pk4[ct], acc_o[dt], 0, 0, 0);
      }
    }
    __builtin_amdgcn_s_setprio(0);

    // write next tile (regs -> other buffer), issue loads for tile it+2
    if (more) {
      *(short8*)&Ks[cur ^ 1][sr * LDT + scc] = nk;
      *(short8*)&Vs[cur ^ 1][sr * LDT + scc] = nv;
      if (it + 2 <= last) {
        int kv2 = kv0 + 128;
        nk = *(const short8*)&kh[(size_t)(kv2 + sr) * DHEAD + scc];
        nv = *(const short8*)&vh[(size_t)sr * S_LEN + kv2 + scc];
      }
    }
    __syncthreads();
    cur ^= 1;
  }

  // epilogue: reduce l across the 4 g-groups, normalize, store
  l += __shfl_xor(l, 16);
  l += __shfl_xor(l, 32);
  float rl = (l > 0.f) ? 1.f / l : 0.f;
#pragma unroll
  for (int dt = 0; dt < 4; ++dt) {
    ushort4 o;
    o.x = f2bf(acc_o[dt][0] * rl);
    o.y = f2bf(acc_o[dt][1] * rl);
    o.z = f2bf(acc_o[dt][2] * rl);
    o.w = f2bf(acc_o[dt][3] * rl);
    *(ushort4*)&O[(size_t)qrow * D_EMB + h * DHEAD + dt * 16 + g * 4] = o;
  }
}

extern "C" void kernel_launch(void* const* d_in, const int* in_sizes, int n_in,
                              void* d_out, int out_size, void* d_ws, size_t ws_size,
                              hipStream_t stream) {
  const float* x = (const float*)d_in[0];
  const float* W_in = (const float*)d_in[1];
  const float* b_in = (const float*)d_in[2];
  const float* W_out = (const float*)d_in[3];
  const float* b_out = (const float*)d_in[4];
  float* out = (float*)d_out;
  ushort* ws = (ushort*)d_ws;

  cvt_bf16_kernel<<<4096, 256, 0, stream>>>(x, ws + OFF_XB, S_LEN * D_EMB);
  transpose_cvt_kernel<<<dim3(N3 / 32, D_EMB / 32), 256, 0, stream>>>(W_in, ws + OFF_WINT, D_EMB, N3);
  transpose_cvt_kernel<<<dim3(D_EMB / 32, D_EMB / 32), 256, 0, stream>>>(W_out, ws + OFF_WOUTT, D_EMB, D_EMB);
  gemm_bt_kernel<0><<<dim3(N3 / 128, S_LEN / 128), 256, 0, stream>>>(
      ws + OFF_XB, ws + OFF_WINT, b_in, ws + OFF_Q, nullptr, N3, D_EMB);
  attn_kernel<<<512, 512, 0, stream>>>(
      ws + OFF_Q, ws + OFF_Q + 4194304u, ws + OFF_Q + 8388608u, ws + OFF_ATTN);
  gemm_bt_kernel<1><<<dim3(D_EMB / 128, S_LEN / 128), 256, 0, stream>>>(
      ws + OFF_ATTN, ws + OFF_WOUTT, b_out, nullptr, out, D_EMB, D_EMB);
}